// Round 3
// baseline (269.689 us; speedup 1.0000x reference)
//
#include <hip/hip_runtime.h>

// RoiAlign / crop_and_resize: B=8, H=64, W=64, C=256, N=512, POOL=7
//
// R7: persistent blocks + y-sorted work order. R5 (sort) and R6 (slice)
// were both null because under HBM saturation the free-running dispatcher
// keeps ~a whole image of blocks live per XCD -> instantaneous read
// footprint = 4 MiB = L2 size -> thrash, regardless of dispatch order.
// Fix: only 512 persistent blocks (64/image, 2/CU); each grid-strides its
// image's 896 row-steps in y-sorted box order. Instantaneous window =
// 64 blocks x 4 rows = ~37 sorted boxes ~= 26 fm rows ~= 1.7 MiB/XCD,
// structurally bounded -> gather reads become L2 hits.
// Revert R6 pair-split (cost +8us): back to R4 full-row waves (one wave =
// one (box,py) row, lane=channel-quad). Keep: %8 image->XCD pin, 28
// hoisted 16B/lane loads, NT 1KB stores, R5's proven bitonic sort.

#define POOL  7
#define B_    8
#define H_    64
#define W_    64
#define C_    256
#define N_    512
#define CW    (C_ / 4)                   // 64 16B-quads per spatial pixel
#define ROWS_PER_IMG (N_ * POOL)         // 3584 rows per image
#define WAVES_PER_BLOCK 4
#define BLOCKS_PER_IMG 64                // persistent blocks per image
#define STEPS_PER_IMG (ROWS_PER_IMG / WAVES_PER_BLOCK)   // 896
#define ITERS (STEPS_PER_IMG / BLOCKS_PER_IMG)           // 14

typedef float v4f __attribute__((ext_vector_type(4)));

// ---- prologue: per-image bitonic sort of 512 boxes by y1 (R5, proven) ---
__global__ __launch_bounds__(512) void sort_boxes_kernel(
    const float* __restrict__ boxes,   // [B,N,4] x1,y1,x2,y2
    int* __restrict__ perm)            // [B,N]
{
    const int b = blockIdx.x;          // 0..7
    const int t = threadIdx.x;         // 0..511
    __shared__ float key[N_];
    __shared__ int   idx[N_];
    key[t] = boxes[((b << 9) + t) * 4 + 1];   // y1
    idx[t] = t;
    __syncthreads();
    for (int k = 2; k <= N_; k <<= 1) {
        for (int j = k >> 1; j > 0; j >>= 1) {
            const int ixj = t ^ j;
            if (ixj > t) {
                const bool up = ((t & k) == 0);
                const float a = key[t], c = key[ixj];
                if (up ? (a > c) : (a < c)) {
                    key[t] = c; key[ixj] = a;
                    const int tmp = idx[t]; idx[t] = idx[ixj]; idx[ixj] = tmp;
                }
            }
            __syncthreads();
        }
    }
    perm[(b << 9) + t] = idx[t];
}

// ---- main kernel: persistent, strided walk in sorted order --------------
__global__ __launch_bounds__(256) void roialign_kernel(
    const float* __restrict__ fm,      // [B,H,W,C]
    const float* __restrict__ boxes,   // [B,N,4] = x1,y1,x2,y2 normalized
    const int*  __restrict__ perm,     // [B,N] y-sorted box order
    float* __restrict__ out)           // [B,N,POOL,POOL,C]
{
    // XCD pin: image b -> XCD b (round-robin block dispatch, 512 blocks).
    const int b    = blockIdx.x & 7;
    const int j    = blockIdx.x >> 3;           // 0..63 persistent slot
    const int wave = threadIdx.x >> 6;          // 0..3
    const int lane = threadIdx.x & 63;          // channel-quad

    const v4f* f4 = (const v4f*)fm;

    for (int t = 0; t < ITERS; ++t) {
        // All 64 blocks of an image walk a contiguous moving window:
        // step = j + 64*t. Window = 64 steps = 256 rows = ~37 sorted boxes.
        const int step = j + (t << 6);          // 0..895
        const int row  = step * WAVES_PER_BLOCK + wave;  // 0..3583
        const int ns   = row / POOL;            // sorted position 0..511
        const int py   = row - ns * POOL;       // 0..6

        const int n = __builtin_amdgcn_readfirstlane(perm[(b << 9) + ns]);

        const float* box = boxes + ((b << 9) + n) * 4;
        const float bx1 = box[0], by1 = box[1], bx2 = box[2], by2 = box[3];

        // Match reference expression order exactly:
        //   ys = y1*(H-1) + i * ((y2-y1)*(H-1)/(POOL-1))
        const float sy  = (by2 - by1) * 63.0f / 6.0f;
        const float sx  = (bx2 - bx1) * 63.0f / 6.0f;
        const float yv  = by1 * 63.0f + (float)py * sy;
        const float x0v = bx1 * 63.0f;

        const float yf = floorf(yv);
        const float fy = yv - yf;
        const int   y0 = (int)yf;
        const int   yt = min(max(y0,     0), H_ - 1);
        const int   yb = min(max(y0 + 1, 0), H_ - 1);
        const bool  vy = (yv >= 0.0f) && (yv <= 63.0f);

        const int rowT = (b * (H_ * W_) + yt * W_) * CW + lane;
        const int rowB = (b * (H_ * W_) + yb * W_) * CW + lane;

        v4f* o4 = (v4f*)out + ((((b << 9) + n) * POOL + py) * POOL) * CW + lane;

        #pragma unroll
        for (int px = 0; px < POOL; ++px) {
            const float xv = x0v + (float)px * sx;
            const float xf = floorf(xv);
            const float fx = xv - xf;
            const int   x0 = (int)xf;
            const int   xl = min(max(x0,     0), W_ - 1);
            const int   xr = min(max(x0 + 1, 0), W_ - 1);
            const bool  valid = vy && (xv >= 0.0f) && (xv <= 63.0f);

            const v4f tl = f4[rowT + xl * CW];
            const v4f tr = f4[rowT + xr * CW];
            const v4f bl = f4[rowB + xl * CW];
            const v4f br = f4[rowB + xr * CW];

            const v4f top = tl + (tr - tl) * fx;
            const v4f bot = bl + (br - bl) * fx;
            v4f o = top + (bot - top) * fy;
            if (!valid) o = (v4f)(0.0f);

            __builtin_nontemporal_store(o, o4 + px * CW);
        }
    }
}

extern "C" void kernel_launch(void* const* d_in, const int* in_sizes, int n_in,
                              void* d_out, int out_size, void* d_ws, size_t ws_size,
                              hipStream_t stream) {
    const float* fm    = (const float*)d_in[0];   // [8,64,64,256] fp32
    const float* boxes = (const float*)d_in[1];   // [8,512,4] fp32
    float* out         = (float*)d_out;           // [8,512,7,7,256] fp32
    int*   perm        = (int*)d_ws;              // [8,512] = 16 KB

    sort_boxes_kernel<<<B_, N_, 0, stream>>>(boxes, perm);

    // 64 persistent blocks per image x 8 images = 512 blocks (2 per CU).
    roialign_kernel<<<BLOCKS_PER_IMG * B_, 256, 0, stream>>>(fm, boxes, perm, out);
}

// Round 4
// 241.779 us; speedup vs baseline: 1.1154x; 1.1154x over previous
//
#include <hip/hip_runtime.h>

// RoiAlign / crop_and_resize: B=8, H=64, W=64, C=256, N=512, POOL=7
//
// R8: LDS row-pair staging. R5/R6/R7 (sort, slice, persistent+sort) all
// null: box heights run up to full-image, so no dispatch order bounds the
// concurrent read footprint below ~L2 size; gather reads kept missing to
// HBM (main kernel 122us == (822MB read + 205MB write)/6.6TB/s).
// Structural fix: one output row needs exactly 2 adjacent fm rows, and
// 2 rows = 128 KiB fits LDS. Prologue counting-sorts the 3584 (box,py)
// items per image by yt=clamp(floor(yv),0,63). Main: one block per
// (image, fm-row-pair bucket); stage rows bk,bk+1 to LDS (each fm row
// fetched <=2x total -> ~67MB fetch), corners read from LDS.
// bucket == yt identically, so top row is always LDS slot 0.
// Keep: image->XCD pin (%8), 1KB coalesced NT stores, exact R4 math.

#define POOL  7
#define B_    8
#define H_    64
#define W_    64
#define C_    256
#define N_    512
#define CW    (C_ / 4)                   // 64 16B-quads per spatial pixel
#define ROWQ  (W_ * CW)                  // 4096 quads per fm row (64 KiB)
#define ITEMS_PER_IMG (N_ * POOL)        // 3584

typedef float v4f __attribute__((ext_vector_type(4)));
typedef unsigned short u16;

// ---- prologue: per-image counting sort of (box,py) items by yt ----------
__global__ __launch_bounds__(512) void bucket_kernel(
    const float* __restrict__ boxes,   // [B,N,4] x1,y1,x2,y2
    int* __restrict__ offs,            // [B,65]
    u16* __restrict__ items)           // [B,3584] packed (n<<3)|py
{
    const int b = blockIdx.x;          // 0..7
    const int n = threadIdx.x;         // 0..511
    __shared__ int hist[H_];
    __shared__ int base[H_];
    __shared__ int cnt[H_];
    if (n < H_) hist[n] = 0;
    __syncthreads();

    const float by1 = boxes[(((b << 9) + n) << 2) + 1];
    const float by2 = boxes[(((b << 9) + n) << 2) + 3];
    // EXACT same expression as main kernel (must produce identical yt):
    const float sy = (by2 - by1) * 63.0f / 6.0f;
    int bk[POOL];
    #pragma unroll
    for (int py = 0; py < POOL; ++py) {
        const float yv = by1 * 63.0f + (float)py * sy;
        const int y0 = (int)floorf(yv);
        bk[py] = min(max(y0, 0), H_ - 1);
        atomicAdd(&hist[bk[py]], 1);
    }
    __syncthreads();
    if (n == 0) {
        int run = 0;
        for (int i = 0; i < H_; ++i) { base[i] = run; run += hist[i]; }
    }
    if (n < H_) cnt[n] = 0;
    __syncthreads();
    #pragma unroll
    for (int py = 0; py < POOL; ++py) {
        const int pos = base[bk[py]] + atomicAdd(&cnt[bk[py]], 1);
        items[b * ITEMS_PER_IMG + pos] = (u16)((n << 3) | py);
    }
    if (n < H_) offs[b * (H_ + 1) + n] = base[n];
    if (n == 0) offs[b * (H_ + 1) + H_] = ITEMS_PER_IMG;
}

// ---- main kernel: one block per (image, row-pair bucket) ----------------
__global__ __launch_bounds__(256) void roialign_kernel(
    const float* __restrict__ fm,      // [B,H,W,C]
    const float* __restrict__ boxes,   // [B,N,4]
    const int*  __restrict__ offs,     // [B,65]
    const u16*  __restrict__ items,    // [B,3584]
    float* __restrict__ out)           // [B,N,POOL,POOL,C]
{
    extern __shared__ v4f lds[];       // 2 rows x 4096 quads = 128 KiB
    const int b    = blockIdx.x & 7;   // image -> XCD pin
    const int bk   = blockIdx.x >> 3;  // fm row bucket 0..63
    const int tid  = threadIdx.x;
    const int wave = tid >> 6;
    const int lane = tid & 63;         // channel-quad
    const v4f* f4  = (const v4f*)fm;

    // Stage rows bk (slot 0) and min(bk+1,63) (slot 1), coalesced.
    {
        const int base0 = (b * H_ + bk) * ROWQ;
        const int base1 = (b * H_ + min(bk + 1, H_ - 1)) * ROWQ;
        #pragma unroll
        for (int k = 0; k < 16; ++k)
            lds[k * 256 + tid] = f4[base0 + k * 256 + tid];
        #pragma unroll
        for (int k = 0; k < 16; ++k)
            lds[ROWQ + k * 256 + tid] = f4[base1 + k * 256 + tid];
    }
    __syncthreads();

    const int start = offs[b * (H_ + 1) + bk];
    const int end   = offs[b * (H_ + 1) + bk + 1];

    for (int it = start + wave; it < end; it += 4) {
        const int code = __builtin_amdgcn_readfirstlane(
                             (int)items[b * ITEMS_PER_IMG + it]);
        const int n  = code >> 3;
        const int py = code & 7;

        const float* box = boxes + (((b << 9) + n) << 2);
        const float bx1 = box[0], by1 = box[1], bx2 = box[2], by2 = box[3];

        // Match reference expression order exactly:
        const float sy  = (by2 - by1) * 63.0f / 6.0f;
        const float sx  = (bx2 - bx1) * 63.0f / 6.0f;
        const float yv  = by1 * 63.0f + (float)py * sy;
        const float x0v = bx1 * 63.0f;

        const float yf = floorf(yv);
        const float fy = yv - yf;
        const int   y0 = (int)yf;
        const int   yt = min(max(y0,     0), H_ - 1);   // == bk by construction
        const int   yb = min(max(y0 + 1, 0), H_ - 1);
        const bool  vy = (yv >= 0.0f) && (yv <= 63.0f);

        const int offB = (yb > yt) ? ROWQ : 0;          // bottom row LDS slot

        v4f* o4 = (v4f*)out + ((((b << 9) + n) * POOL + py) * POOL) * CW + lane;

        #pragma unroll
        for (int px = 0; px < POOL; ++px) {
            const float xv = x0v + (float)px * sx;
            const float xf = floorf(xv);
            const float fx = xv - xf;
            const int   x0 = (int)xf;
            const int   xl = min(max(x0,     0), W_ - 1);
            const int   xr = min(max(x0 + 1, 0), W_ - 1);
            const bool  valid = vy && (xv >= 0.0f) && (xv <= 63.0f);

            const v4f tl = lds[       xl * CW + lane];
            const v4f tr = lds[       xr * CW + lane];
            const v4f bl = lds[offB + xl * CW + lane];
            const v4f br = lds[offB + xr * CW + lane];

            const v4f top = tl + (tr - tl) * fx;
            const v4f bot = bl + (br - bl) * fx;
            v4f o = top + (bot - top) * fy;
            if (!valid) o = (v4f)(0.0f);

            __builtin_nontemporal_store(o, o4 + px * CW);
        }
    }
}

extern "C" void kernel_launch(void* const* d_in, const int* in_sizes, int n_in,
                              void* d_out, int out_size, void* d_ws, size_t ws_size,
                              hipStream_t stream) {
    const float* fm    = (const float*)d_in[0];   // [8,64,64,256] fp32
    const float* boxes = (const float*)d_in[1];   // [8,512,4] fp32
    float* out         = (float*)d_out;           // [8,512,7,7,256] fp32

    int* offs  = (int*)d_ws;                      // [8][65] ints (2080 B)
    u16* items = (u16*)((char*)d_ws + 4096);      // [8][3584] u16 (57 KB)

    bucket_kernel<<<B_, N_, 0, stream>>>(boxes, offs, items);

    // 64 buckets x 8 images = 512 blocks; 128 KiB dynamic LDS each.
    roialign_kernel<<<H_ * B_, 256, 2 * ROWQ * sizeof(v4f), stream>>>(
        fm, boxes, offs, items, out);
}

// Round 5
// 233.628 us; speedup vs baseline: 1.1544x; 1.0349x over previous
//
#include <hip/hip_runtime.h>

// RoiAlign / crop_and_resize: B=8, H=64, W=64, C=256, N=512, POOL=7
//
// R9: plain (L2 write-back) stores instead of nontemporal. R8 falsified
// the read-bound theory: LDS-staging ALL gather reads (fetch 600->67MB)
// moved the main kernel only 122->~112us. The cost common to every
// ~110-135us variant is 802,816 NT store instrs (205MB). Theory: nt =
// no-allocate, each store retires to fabric/HBM against a fixed per-CU
// outstanding-write credit pool (~16) at ~900cy -> ~74us serialized,
// independent of wave count (credits are per-CU, waves don't add them).
// Retro-explains R6 (+8us when store count doubled) and all null
// read-side fixes. Plain stores complete at L2 (writeback drains at full
// BW); safe NOW because R8's LDS staging freed L2 of all read traffic.
// Also: 512 thr/block (8 waves/CU, was 4) for issue/latency hiding.
// Keep: bucket prologue, row-pair 128KiB LDS staging, image->XCD pin,
// exact reference math (bit-identical output).

#define POOL  7
#define B_    8
#define H_    64
#define W_    64
#define C_    256
#define N_    512
#define CW    (C_ / 4)                   // 64 16B-quads per spatial pixel
#define ROWQ  (W_ * CW)                  // 4096 quads per fm row (64 KiB)
#define ITEMS_PER_IMG (N_ * POOL)        // 3584

typedef float v4f __attribute__((ext_vector_type(4)));
typedef unsigned short u16;

// ---- prologue: per-image counting sort of (box,py) items by yt ----------
__global__ __launch_bounds__(512) void bucket_kernel(
    const float* __restrict__ boxes,   // [B,N,4] x1,y1,x2,y2
    int* __restrict__ offs,            // [B,65]
    u16* __restrict__ items)           // [B,3584] packed (n<<3)|py
{
    const int b = blockIdx.x;          // 0..7
    const int n = threadIdx.x;         // 0..511
    __shared__ int hist[H_];
    __shared__ int base[H_];
    __shared__ int cnt[H_];
    if (n < H_) hist[n] = 0;
    __syncthreads();

    const float by1 = boxes[(((b << 9) + n) << 2) + 1];
    const float by2 = boxes[(((b << 9) + n) << 2) + 3];
    // EXACT same expression as main kernel (must produce identical yt):
    const float sy = (by2 - by1) * 63.0f / 6.0f;
    int bk[POOL];
    #pragma unroll
    for (int py = 0; py < POOL; ++py) {
        const float yv = by1 * 63.0f + (float)py * sy;
        const int y0 = (int)floorf(yv);
        bk[py] = min(max(y0, 0), H_ - 1);
        atomicAdd(&hist[bk[py]], 1);
    }
    __syncthreads();
    if (n == 0) {
        int run = 0;
        for (int i = 0; i < H_; ++i) { base[i] = run; run += hist[i]; }
    }
    if (n < H_) cnt[n] = 0;
    __syncthreads();
    #pragma unroll
    for (int py = 0; py < POOL; ++py) {
        const int pos = base[bk[py]] + atomicAdd(&cnt[bk[py]], 1);
        items[b * ITEMS_PER_IMG + pos] = (u16)((n << 3) | py);
    }
    if (n < H_) offs[b * (H_ + 1) + n] = base[n];
    if (n == 0) offs[b * (H_ + 1) + H_] = ITEMS_PER_IMG;
}

// ---- main kernel: one block per (image, row-pair bucket) ----------------
__global__ __launch_bounds__(512) void roialign_kernel(
    const float* __restrict__ fm,      // [B,H,W,C]
    const float* __restrict__ boxes,   // [B,N,4]
    const int*  __restrict__ offs,     // [B,65]
    const u16*  __restrict__ items,    // [B,3584]
    float* __restrict__ out)           // [B,N,POOL,POOL,C]
{
    extern __shared__ v4f lds[];       // 2 rows x 4096 quads = 128 KiB
    const int b    = blockIdx.x & 7;   // image -> XCD pin
    const int bk   = blockIdx.x >> 3;  // fm row bucket 0..63
    const int tid  = threadIdx.x;      // 0..511
    const int wave = tid >> 6;         // 0..7
    const int lane = tid & 63;         // channel-quad
    const v4f* f4  = (const v4f*)fm;

    // Stage rows bk (slot 0) and min(bk+1,63) (slot 1), coalesced.
    {
        const int base0 = (b * H_ + bk) * ROWQ;
        const int base1 = (b * H_ + min(bk + 1, H_ - 1)) * ROWQ;
        #pragma unroll
        for (int k = 0; k < 8; ++k)
            lds[k * 512 + tid] = f4[base0 + k * 512 + tid];
        #pragma unroll
        for (int k = 0; k < 8; ++k)
            lds[ROWQ + k * 512 + tid] = f4[base1 + k * 512 + tid];
    }
    __syncthreads();

    const int start = offs[b * (H_ + 1) + bk];
    const int end   = offs[b * (H_ + 1) + bk + 1];

    for (int it = start + wave; it < end; it += 8) {
        const int code = __builtin_amdgcn_readfirstlane(
                             (int)items[b * ITEMS_PER_IMG + it]);
        const int n  = code >> 3;
        const int py = code & 7;

        const float* box = boxes + (((b << 9) + n) << 2);
        const float bx1 = box[0], by1 = box[1], bx2 = box[2], by2 = box[3];

        // Match reference expression order exactly:
        const float sy  = (by2 - by1) * 63.0f / 6.0f;
        const float sx  = (bx2 - bx1) * 63.0f / 6.0f;
        const float yv  = by1 * 63.0f + (float)py * sy;
        const float x0v = bx1 * 63.0f;

        const float yf = floorf(yv);
        const float fy = yv - yf;
        const int   y0 = (int)yf;
        const int   yt = min(max(y0,     0), H_ - 1);   // == bk by construction
        const int   yb = min(max(y0 + 1, 0), H_ - 1);
        const bool  vy = (yv >= 0.0f) && (yv <= 63.0f);

        const int offB = (yb > yt) ? ROWQ : 0;          // bottom row LDS slot

        v4f* o4 = (v4f*)out + ((((b << 9) + n) * POOL + py) * POOL) * CW + lane;

        #pragma unroll
        for (int px = 0; px < POOL; ++px) {
            const float xv = x0v + (float)px * sx;
            const float xf = floorf(xv);
            const float fx = xv - xf;
            const int   x0 = (int)xf;
            const int   xl = min(max(x0,     0), W_ - 1);
            const int   xr = min(max(x0 + 1, 0), W_ - 1);
            const bool  valid = vy && (xv >= 0.0f) && (xv <= 63.0f);

            const v4f tl = lds[       xl * CW + lane];
            const v4f tr = lds[       xr * CW + lane];
            const v4f bl = lds[offB + xl * CW + lane];
            const v4f br = lds[offB + xr * CW + lane];

            const v4f top = tl + (tr - tl) * fx;
            const v4f bot = bl + (br - bl) * fx;
            v4f o = top + (bot - top) * fy;
            if (!valid) o = (v4f)(0.0f);

            o4[px * CW] = o;               // plain store: completes at L2
        }
    }
}

extern "C" void kernel_launch(void* const* d_in, const int* in_sizes, int n_in,
                              void* d_out, int out_size, void* d_ws, size_t ws_size,
                              hipStream_t stream) {
    const float* fm    = (const float*)d_in[0];   // [8,64,64,256] fp32
    const float* boxes = (const float*)d_in[1];   // [8,512,4] fp32
    float* out         = (float*)d_out;           // [8,512,7,7,256] fp32

    int* offs  = (int*)d_ws;                      // [8][65] ints (2080 B)
    u16* items = (u16*)((char*)d_ws + 4096);      // [8][3584] u16 (57 KB)

    bucket_kernel<<<B_, N_, 0, stream>>>(boxes, offs, items);

    // 64 buckets x 8 images = 512 blocks; 128 KiB dynamic LDS each.
    roialign_kernel<<<H_ * B_, 512, 2 * ROWQ * sizeof(v4f), stream>>>(
        fm, boxes, offs, items, out);
}

// Round 6
// 231.453 us; speedup vs baseline: 1.1652x; 1.0094x over previous
//
#include <hip/hip_runtime.h>

// RoiAlign / crop_and_resize: B=8, H=64, W=64, C=256, N=512, POOL=7
//
// R10: execution-granularity attack. Ledger so far: read-side fixes
// (sort/slice/persistent/full-LDS) = -10us total; NT->plain stores = -8us.
// Main kernel ~105us vs component-model ~50us -> ~50us unexplained.
// Suspect: R9's 128KiB LDS -> 1 block/CU: unhidden 5us staging stall x2
// rounds, bucket-size imbalance over only 512 blocks, 8 waves/CU, plus a
// serial prologue dispatch. Fix: stage ONE row (64KiB, row bk) per block;
// bl/br corners read from global (R8 proved global-vs-LDS reads ~= 10us
// on 2x the volume); bucketing fused into the kernel (no prologue);
// 1024 blocks = 2 per bucket split by (n+py)&1 parity (identity-based ->
// exact once-per-item across nondeterministic list orders); 72.7KiB LDS
// -> 2 blocks/CU, 16 waves/CU, 4 scheduling rounds.
// Robustness: process phase uses yt:=bk, yb:=min(bk+1,63), fy:=yv-bk
// (continuous at bucket boundaries -> build/process 1-ulp divergence
// cannot select a wrong staged row).
// Keep: image->XCD pin (%8), plain L2 writeback stores, 1KB/wave stores,
// exact reference x-path math.

#define POOL  7
#define B_    8
#define H_    64
#define W_    64
#define C_    256
#define N_    512
#define CW    (C_ / 4)                   // 64 16B-quads per spatial pixel
#define ROWQ  (W_ * CW)                  // 4096 quads per fm row (64 KiB)
#define MAXI  3584                       // safe upper bound for one list

typedef float v4f __attribute__((ext_vector_type(4)));
typedef unsigned short u16;

__global__ __launch_bounds__(512) void roialign_kernel(
    const float* __restrict__ fm,      // [B,H,W,C]
    const float* __restrict__ boxes,   // [B,N,4] x1,y1,x2,y2 normalized
    float* __restrict__ out)           // [B,N,POOL,POOL,C]
{
    extern __shared__ v4f lds[];           // [ROWQ] staged row bk (64 KiB)
    u16* list = (u16*)(lds + ROWQ);        // [MAXI] item codes (7 KiB)
    __shared__ int cnt;

    const int b    = blockIdx.x & 7;       // image -> XCD pin
    const int u    = blockIdx.x >> 3;      // 0..127
    const int bk   = u >> 1;               // fm row bucket 0..63
    const int half = u & 1;                // item-parity half
    const int tid  = threadIdx.x;          // 0..511
    const int wave = tid >> 6;             // 0..7
    const int lane = tid & 63;             // channel-quad
    const v4f* f4  = (const v4f*)fm;

    if (tid == 0) cnt = 0;
    __syncthreads();

    // ---- stage row bk (full channels, 64 KiB), coalesced ---------------
    {
        const int base0 = (b * H_ + bk) * ROWQ;
        #pragma unroll
        for (int k = 0; k < 8; ++k)
            lds[k * 512 + tid] = f4[base0 + k * 512 + tid];
    }

    // ---- fused bucketing: thread n scans its box's 7 samples -----------
    {
        const int n = tid;                 // 0..511
        const float by1 = boxes[(((b << 9) + n) << 2) + 1];
        const float by2 = boxes[(((b << 9) + n) << 2) + 3];
        const float sy  = (by2 - by1) * 63.0f / 6.0f;
        #pragma unroll
        for (int py = 0; py < POOL; ++py) {
            const float yv = by1 * 63.0f + (float)py * sy;
            const int y0  = (int)floorf(yv);
            const int bkk = min(max(y0, 0), H_ - 1);
            if (bkk == bk && (((n + py) & 1) == half)) {
                const int pos = atomicAdd(&cnt, 1);
                list[pos] = (u16)((n << 3) | py);
            }
        }
    }
    __syncthreads();

    const int nItems = cnt;
    const int yb       = min(bk + 1, H_ - 1);
    const int rowBbase = (b * (H_ * W_) + yb * W_) * CW + lane;
    const float yfB    = (float)bk;

    for (int it = wave; it < nItems; it += 8) {
        const int code = __builtin_amdgcn_readfirstlane((int)list[it]);
        const int n  = code >> 3;
        const int py = code & 7;

        const float* box = boxes + (((b << 9) + n) << 2);
        const float bx1 = box[0], by1 = box[1], bx2 = box[2], by2 = box[3];

        // Match reference expression order exactly (x path), y via bucket:
        const float sy  = (by2 - by1) * 63.0f / 6.0f;
        const float sx  = (bx2 - bx1) * 63.0f / 6.0f;
        const float yv  = by1 * 63.0f + (float)py * sy;
        const float x0v = bx1 * 63.0f;

        // yt == bk by bucketing; fy relative to bk is continuous across
        // any 1-ulp build/process divergence at integer boundaries.
        const float fy = yv - yfB;
        const bool  vy = (yv >= 0.0f) && (yv <= 63.0f);

        v4f* o4 = (v4f*)out + ((((b << 9) + n) * POOL + py) * POOL) * CW + lane;

        #pragma unroll
        for (int px = 0; px < POOL; ++px) {
            const float xv = x0v + (float)px * sx;
            const float xf = floorf(xv);
            const float fx = xv - xf;
            const int   x0 = (int)xf;
            const int   xl = min(max(x0,     0), W_ - 1);
            const int   xr = min(max(x0 + 1, 0), W_ - 1);
            const bool  valid = vy && (xv >= 0.0f) && (xv <= 63.0f);

            const v4f tl = lds[xl * CW + lane];          // row bk from LDS
            const v4f tr = lds[xr * CW + lane];
            const v4f bl = f4[rowBbase + xl * CW];       // row bk+1 from L2
            const v4f br = f4[rowBbase + xr * CW];

            const v4f top = tl + (tr - tl) * fx;
            const v4f bot = bl + (br - bl) * fx;
            v4f o = top + (bot - top) * fy;
            if (!valid) o = (v4f)(0.0f);

            o4[px * CW] = o;               // plain store: completes at L2
        }
    }
}

extern "C" void kernel_launch(void* const* d_in, const int* in_sizes, int n_in,
                              void* d_out, int out_size, void* d_ws, size_t ws_size,
                              hipStream_t stream) {
    const float* fm    = (const float*)d_in[0];   // [8,64,64,256] fp32
    const float* boxes = (const float*)d_in[1];   // [8,512,4] fp32
    float* out         = (float*)d_out;           // [8,512,7,7,256] fp32

    // 2 blocks per (image, bucket): 64 buckets x 2 x 8 images = 1024 blocks.
    // Dynamic LDS: 64 KiB row + 7 KiB list = 72704 B -> 2 blocks/CU.
    const size_t ldsB = ROWQ * sizeof(v4f) + MAXI * sizeof(u16);
    roialign_kernel<<<H_ * 2 * B_, 512, ldsB, stream>>>(fm, boxes, out);
}